// Round 2
// baseline (771.452 us; speedup 1.0000x reference)
//
#include <hip/hip_runtime.h>
#include <hip/hip_bf16.h>

typedef __hip_bfloat16 bf16;

// ---------------- dtype probe + canonicalization ----------------
// flags[0] = 1 if float tensors are stored as f32 (else bf16)
// flags[1] = 1 if edge_index is stored as int64 (else int32)

__global__ __launch_bounds__(256) void k_detect(const unsigned short* __restrict__ xr,
                                                const int* __restrict__ er,
                                                int* __restrict__ flags) {
    __shared__ int sbad, snz;
    int tid = threadIdx.x;
    if (tid == 0) { sbad = 0; snz = 0; }
    __syncthreads();
    int bad = 0, nz = 0;
    for (int i = tid; i < 1024; i += 256) {
        unsigned short w = xr[2 * i];          // f32 storage: low mantissa half (uniform); bf16: real value
        int ex = (w >> 7) & 0xFF;
        if (ex < 110 || ex > 135) bad++;
        if (er[2 * i + 1] != 0) nz++;          // int64 storage: high words of small values == 0
    }
    atomicAdd(&sbad, bad);
    atomicAdd(&snz, nz);
    __syncthreads();
    if (tid == 0) {
        flags[0] = (sbad > 256) ? 1 : 0;
        flags[1] = (snz < 512) ? 1 : 0;
    }
}

struct CvtArgs { const void* p[19]; int sz[19]; };

__global__ __launch_bounds__(256) void k_convert(CvtArgs a, const int* __restrict__ flags,
                                                 float* __restrict__ dst, int total) {
    int t = blockIdx.x * 256 + threadIdx.x;
    if (t >= total) return;
    int isf32 = flags[0];
    int base = 0, seg = -1, off = 0;
#pragma unroll
    for (int i = 0; i < 19; i++) {
        if (seg < 0 && t < base + a.sz[i]) { seg = i; off = t - base; }
        base += a.sz[i];
    }
    const void* p = a.p[seg];
    float v = isf32 ? ((const float*)p)[off] : __bfloat162float(((const bf16*)p)[off]);
    dst[t] = v;
}

static __device__ __forceinline__ int ld_edge(const int* er, size_t i, int idx64) {
    return idx64 ? er[2 * i] : er[i];
}

// ---------------- CSR build ----------------

__global__ __launch_bounds__(256) void k_hist(const int* __restrict__ er, const int* __restrict__ flags,
                                              int* __restrict__ indeg, int E) {
    int e = blockIdx.x * 256 + threadIdx.x;
    if (e >= E) return;
    int idx64 = flags[1];
    int d = ld_edge(er, (size_t)E + e, idx64);
    atomicAdd(&indeg[d], 1);
}

__global__ __launch_bounds__(256) void k_scan1(const int* __restrict__ in, int* __restrict__ out,
                                               int* __restrict__ bsums, int n) {
    __shared__ int sm[256];
    int i = blockIdx.x * 256 + threadIdx.x;
    int v = (i < n) ? in[i] : 0;
    sm[threadIdx.x] = v;
    __syncthreads();
    for (int d = 1; d < 256; d <<= 1) {
        int t = (threadIdx.x >= d) ? sm[threadIdx.x - d] : 0;
        __syncthreads();
        sm[threadIdx.x] += t;
        __syncthreads();
    }
    if (i < n) out[i] = sm[threadIdx.x] - v;  // exclusive
    if (threadIdx.x == 255) bsums[blockIdx.x] = sm[255];
}

__global__ __launch_bounds__(1024) void k_scan2(int* __restrict__ bsums, int nb,
                                                int* __restrict__ csr_off, int N, int total) {
    __shared__ int sm[1024];
    int v = (threadIdx.x < nb) ? bsums[threadIdx.x] : 0;
    sm[threadIdx.x] = v;
    __syncthreads();
    for (int d = 1; d < 1024; d <<= 1) {
        int t = (threadIdx.x >= d) ? sm[threadIdx.x - d] : 0;
        __syncthreads();
        sm[threadIdx.x] += t;
        __syncthreads();
    }
    if (threadIdx.x < nb) bsums[threadIdx.x] = sm[threadIdx.x] - v;
    if (threadIdx.x == 0) csr_off[N] = total;
}

__global__ __launch_bounds__(256) void k_scan3(int* __restrict__ out, const int* __restrict__ bsums, int n) {
    int i = blockIdx.x * 256 + threadIdx.x;
    if (i < n) out[i] += bsums[blockIdx.x];
}

__global__ __launch_bounds__(256) void k_scatter(const int* __restrict__ er, const int* __restrict__ flags,
                                                 const int* __restrict__ off, int* __restrict__ cur,
                                                 int* __restrict__ csr, int E) {
    int e = blockIdx.x * 256 + threadIdx.x;
    if (e >= E) return;
    int idx64 = flags[1];
    int s = ld_edge(er, (size_t)e, idx64);
    int d = ld_edge(er, (size_t)E + e, idx64);
    int pos = off[d] + atomicAdd(&cur[d], 1);
    csr[pos] = s;
}

// ---------------- Layer 1: GATConv(3, 16, heads=4) ----------------

// one wave (64 lanes) per node; lane = head*16 + chan
__global__ __launch_bounds__(256) void k_l1_transform(const float* __restrict__ x, const float* __restrict__ W1,
                                                      const float* __restrict__ att_s, const float* __restrict__ att_d,
                                                      float* __restrict__ h1, float* __restrict__ as1,
                                                      float* __restrict__ ad1, int N) {
    int tid = threadIdx.x;
    int node = blockIdx.x * 4 + (tid >> 6);
    if (node >= N) return;
    int lane = tid & 63;
    float x0 = x[node * 3 + 0];
    float x1 = x[node * 3 + 1];
    float x2 = x[node * 3 + 2];
    float h = x0 * W1[lane] + x1 * W1[64 + lane] + x2 * W1[128 + lane];
    h1[(size_t)node * 64 + lane] = h;
    float ts = h * att_s[lane];   // att_src1 is (4,16) flat == lane
    float td = h * att_d[lane];
    for (int m = 8; m >= 1; m >>= 1) { ts += __shfl_xor(ts, m); td += __shfl_xor(td, m); }
    if ((lane & 15) == 0) {
        as1[node * 4 + (lane >> 4)] = ts;
        ad1[node * 4 + (lane >> 4)] = td;
    }
}

__global__ __launch_bounds__(256) void k_l1_agg(const float* __restrict__ h1, const float* __restrict__ as1,
                                                const float* __restrict__ ad1, const int* __restrict__ off,
                                                const int* __restrict__ csr, const float* __restrict__ b1,
                                                float* __restrict__ x1, int N) {
    int tid = threadIdx.x;
    int node = blockIdx.x * 4 + (tid >> 6);
    if (node >= N) return;
    int lane = tid & 63;
    int h = lane >> 4;
    float ad = ad1[node * 4 + h];
    float acc = 0.f, den = 0.f;
    int e0 = off[node], e1 = off[node + 1];
    // jj == e0-1 is the self-loop (s = node); then the real in-edges
    for (int jj = e0 - 1; jj < e1; ++jj) {
        int s = (jj < e0) ? node : csr[jj];
        float z = as1[s * 4 + h] + ad;
        z = (z > 0.f) ? z : 0.2f * z;   // leaky_relu 0.2
        float w = __expf(z);
        den += w;
        acc += w * h1[(size_t)s * 64 + lane];
    }
    float o = acc / (den + 1e-16f) + b1[lane];
    x1[(size_t)node * 64 + lane] = (o > 0.f) ? o : 0.f;   // relu
}

// ---------------- Layer 2: GATv2Conv(64, 16, heads=2) ----------------

// one wave per node; lanes 0..31 -> hl outputs, 32..63 -> hr outputs
__global__ __launch_bounds__(256) void k_l2_transform(const float* __restrict__ x1,
                                                      const float* __restrict__ W2l, const float* __restrict__ b2l,
                                                      const float* __restrict__ W2r, const float* __restrict__ b2r,
                                                      float* __restrict__ hl, float* __restrict__ hr, int N) {
    __shared__ float xs[4][64];
    int tid = threadIdx.x;
    int r = tid >> 6, c64 = tid & 63;
    int node = blockIdx.x * 4 + r;
    xs[r][c64] = (node < N) ? x1[(size_t)node * 64 + c64] : 0.f;
    __syncthreads();
    if (node >= N) return;
    int half = (tid >> 5) & 1;
    int j = tid & 31;
    const float* W = half ? W2r : W2l;
    float acc = half ? b2r[j] : b2l[j];
#pragma unroll
    for (int k = 0; k < 64; ++k) acc += xs[r][k] * W[k * 32 + j];
    (half ? hr : hl)[(size_t)node * 32 + j] = acc;
}

// 32 lanes per node (2 nodes per wave); lane = head*16 + chan
__global__ __launch_bounds__(256) void k_l2_agg(const float* __restrict__ hl, const float* __restrict__ hr,
                                                const float* __restrict__ att2, const float* __restrict__ b2,
                                                const int* __restrict__ off, const int* __restrict__ csr,
                                                float* __restrict__ x2, int N) {
    int tid = threadIdx.x;
    int node = blockIdx.x * 8 + (tid >> 5);
    if (node >= N) return;
    int sl = tid & 31;
    float hrd = hr[(size_t)node * 32 + sl];
    float a2 = att2[sl];          // att2 is (2,16) flat == sl
    float acc = 0.f, den = 0.f;
    int e0 = off[node], e1 = off[node + 1];
    for (int jj = e0 - 1; jj < e1; ++jj) {
        int s = (jj < e0) ? node : csr[jj];
        float hls = hl[(size_t)s * 32 + sl];
        float e = hls + hrd;
        e = (e > 0.f) ? e : 0.2f * e;
        float t = e * a2;
        t += __shfl_xor(t, 1); t += __shfl_xor(t, 2);
        t += __shfl_xor(t, 4); t += __shfl_xor(t, 8);
        float w = __expf(t);
        den += w;
        acc += w * hls;
    }
    x2[(size_t)node * 32 + sl] = acc / (den + 1e-16f) + b2[sl];
}

// ---------------- Layer 3: TransformerConv(32, 7, heads=1) ----------------

// 32 lanes per node; j<28 active: m = j/7 selects q/k/v/skip, c = j%7
__global__ __launch_bounds__(256) void k_l3_transform(const float* __restrict__ x2,
                                                      const float* __restrict__ Wq, const float* __restrict__ bq,
                                                      const float* __restrict__ Wk, const float* __restrict__ bk,
                                                      const float* __restrict__ Wv, const float* __restrict__ bv,
                                                      const float* __restrict__ Wsk, const float* __restrict__ bsk,
                                                      float* __restrict__ Q, float* __restrict__ K,
                                                      float* __restrict__ V, float* __restrict__ SK, int N) {
    __shared__ float xs[8][32];
    int tid = threadIdx.x;
    int r = tid >> 5, cc = tid & 31;
    int node = blockIdx.x * 8 + r;
    xs[r][cc] = (node < N) ? x2[(size_t)node * 32 + cc] : 0.f;
    __syncthreads();
    if (node >= N) return;
    int j = tid & 31;
    if (j >= 28) return;
    int m = j / 7, c = j - m * 7;
    const float* W = (m == 0) ? Wq : (m == 1) ? Wk : (m == 2) ? Wv : Wsk;
    const float* B = (m == 0) ? bq : (m == 1) ? bk : (m == 2) ? bv : bsk;
    float acc = B[c];
#pragma unroll
    for (int k = 0; k < 32; ++k) acc += xs[r][k] * W[k * 7 + c];
    float* outp = (m == 0) ? Q : (m == 1) ? K : (m == 2) ? V : SK;
    outp[(size_t)node * 7 + c] = acc;
}

// 8 lanes per node (8 nodes per wave); no self-loops in layer 3
__global__ __launch_bounds__(256) void k_l3_agg(const float* __restrict__ Q, const float* __restrict__ K,
                                                const float* __restrict__ V, const float* __restrict__ SK,
                                                const int* __restrict__ off, const int* __restrict__ csr,
                                                float* __restrict__ out, int N) {
    int tid = threadIdx.x;
    int node = blockIdx.x * 32 + (tid >> 3);
    if (node >= N) return;
    int sl = tid & 7;
    bool act = sl < 7;
    float qd = act ? Q[(size_t)node * 7 + sl] : 0.f;
    float acc = 0.f, den = 0.f;
    int e0 = off[node], e1 = off[node + 1];
    const float scale = 0.3779644730092272f;  // 1/sqrt(7)
    for (int jj = e0; jj < e1; ++jj) {
        int s = csr[jj];
        float t = act ? qd * K[(size_t)s * 7 + sl] : 0.f;
        t += __shfl_xor(t, 1); t += __shfl_xor(t, 2); t += __shfl_xor(t, 4);
        float w = __expf(t * scale);
        den += w;
        if (act) acc += w * V[(size_t)s * 7 + sl];
    }
    if (act) out[(size_t)node * 7 + sl] = acc / (den + 1e-16f) + SK[(size_t)node * 7 + sl];
}

// ---------------- launcher ----------------

extern "C" void kernel_launch(void* const* d_in, const int* in_sizes, int n_in,
                              void* d_out, int out_size, void* d_ws, size_t ws_size,
                              hipStream_t stream) {
    const int* ei = (const int*)d_in[1];
    float* out = (float*)d_out;

    int N = in_sizes[0] / 3;
    int E = in_sizes[1] / 2;
    int nb = (N + 255) / 256;   // assumed <= 1024 (N <= 262144)

    char* ws = (char*)d_ws;
    size_t o = 0;
    auto take = [&](size_t bytes) -> char* {
        char* p = ws + o;
        o = (o + bytes + 255) & ~(size_t)255;
        return p;
    };
    int*   flags   = (int*)take(64);
    // canonical f32 inputs: [x | W1 | att_s | att_d | b1 | W2l | b2l | W2r | b2r | att2 | b2 | Wq..bsk]
    int total_f = 0;
    for (int i = 0; i < 20; ++i) if (i != 1) total_f += in_sizes[i];
    float* canon  = (float*)take((size_t)total_f * 4);
    int*   csr_off = (int*)take((size_t)(N + 1) * 4);
    int*   indeg   = (int*)take((size_t)N * 4);
    int*   cursor  = (int*)take((size_t)N * 4);
    int*   bsums   = (int*)take((size_t)nb * 4);
    int*   csr_src = (int*)take((size_t)E * 4);
    float* bufA    = (float*)take((size_t)N * 64 * 4);  // h1 -> hl|hr -> q|k|v|skip
    float* as1     = (float*)take((size_t)N * 4 * 4);
    float* ad1     = (float*)take((size_t)N * 4 * 4);
    float* bufB    = (float*)take((size_t)N * 64 * 4);  // x1 -> x2
    (void)ws_size; (void)n_in; (void)out_size;

    // host-side prefix offsets into canon, in input order (skipping edge_index)
    CvtArgs ca;
    const float* cp[20];
    {
        int off_ = 0, k = 0;
        for (int i = 0; i < 20; ++i) {
            if (i == 1) { cp[i] = nullptr; continue; }
            ca.p[k] = d_in[i];
            ca.sz[k] = in_sizes[i];
            cp[i] = canon + off_;
            off_ += in_sizes[i];
            ++k;
        }
    }

    hipMemsetAsync(indeg, 0, (size_t)N * 4, stream);
    hipMemsetAsync(cursor, 0, (size_t)N * 4, stream);

    k_detect<<<1, 256, 0, stream>>>((const unsigned short*)d_in[0], ei, flags);
    k_convert<<<(total_f + 255) / 256, 256, 0, stream>>>(ca, flags, canon, total_f);

    int ge = (E + 255) / 256;
    k_hist<<<ge, 256, 0, stream>>>(ei, flags, indeg, E);
    k_scan1<<<nb, 256, 0, stream>>>(indeg, csr_off, bsums, N);
    k_scan2<<<1, 1024, 0, stream>>>(bsums, nb, csr_off, N, E);
    k_scan3<<<nb, 256, 0, stream>>>(csr_off, bsums, N);
    k_scatter<<<ge, 256, 0, stream>>>(ei, flags, csr_off, cursor, csr_src, E);

    const float* xf  = cp[0];
    const float* W1  = cp[2];
    const float* asf = cp[3];
    const float* adf = cp[4];
    const float* b1  = cp[5];

    float* h1 = bufA;
    k_l1_transform<<<(N + 3) / 4, 256, 0, stream>>>(xf, W1, asf, adf, h1, as1, ad1, N);
    float* x1 = bufB;
    k_l1_agg<<<(N + 3) / 4, 256, 0, stream>>>(h1, as1, ad1, csr_off, csr_src, b1, x1, N);

    float* hl = bufA;
    float* hr = bufA + (size_t)N * 32;
    k_l2_transform<<<(N + 3) / 4, 256, 0, stream>>>(x1, cp[6], cp[7], cp[8], cp[9], hl, hr, N);
    float* x2 = bufB;
    k_l2_agg<<<(N + 7) / 8, 256, 0, stream>>>(hl, hr, cp[10], cp[11], csr_off, csr_src, x2, N);

    float* Q  = bufA;
    float* K  = bufA + (size_t)N * 7;
    float* V  = bufA + (size_t)N * 14;
    float* SK = bufA + (size_t)N * 21;
    k_l3_transform<<<(N + 7) / 8, 256, 0, stream>>>(x2, cp[12], cp[13], cp[14], cp[15], cp[16], cp[17],
                                                    cp[18], cp[19], Q, K, V, SK, N);
    k_l3_agg<<<(N + 31) / 32, 256, 0, stream>>>(Q, K, V, SK, csr_off, csr_src, out, N);
}

// Round 3
// 653.383 us; speedup vs baseline: 1.1807x; 1.1807x over previous
//
#include <hip/hip_runtime.h>
#include <hip/hip_bf16.h>

typedef __hip_bfloat16 bf16;

static __device__ __forceinline__ float us2f(unsigned short u) {
    union { unsigned int i; float f; } c; c.i = ((unsigned int)u) << 16; return c.f;
}
static __device__ __forceinline__ unsigned short f2us(float f) {
    union { float f; unsigned int i; } c; c.f = f;
    unsigned int r = c.i + 0x7FFF + ((c.i >> 16) & 1);   // round-to-nearest-even
    return (unsigned short)(r >> 16);
}

// ---------------- dtype probe + canonicalization ----------------
// flags[0] = 1 if float tensors are stored as f32 (else bf16)
// flags[1] = 1 if edge_index is stored as int64 (else int32)

__global__ __launch_bounds__(256) void k_detect(const unsigned short* __restrict__ xr,
                                                const int* __restrict__ er,
                                                int* __restrict__ flags) {
    __shared__ int sbad, snz;
    int tid = threadIdx.x;
    if (tid == 0) { sbad = 0; snz = 0; }
    __syncthreads();
    int bad = 0, nz = 0;
    for (int i = tid; i < 1024; i += 256) {
        unsigned short w = xr[2 * i];          // f32 storage: low mantissa half (uniform); bf16: real value
        int ex = (w >> 7) & 0xFF;
        if (ex < 110 || ex > 135) bad++;
        if (er[2 * i + 1] != 0) nz++;          // int64 storage: high words of small values == 0
    }
    atomicAdd(&sbad, bad);
    atomicAdd(&snz, nz);
    __syncthreads();
    if (tid == 0) {
        flags[0] = (sbad > 256) ? 1 : 0;
        flags[1] = (snz < 512) ? 1 : 0;
    }
}

struct CvtArgs { const void* p[19]; int sz[19]; };

__global__ __launch_bounds__(256) void k_convert(CvtArgs a, const int* __restrict__ flags,
                                                 float* __restrict__ dst, int total) {
    int t = blockIdx.x * 256 + threadIdx.x;
    if (t >= total) return;
    int isf32 = flags[0];
    int base = 0, seg = -1, off = 0;
#pragma unroll
    for (int i = 0; i < 19; i++) {
        if (seg < 0 && t < base + a.sz[i]) { seg = i; off = t - base; }
        base += a.sz[i];
    }
    const void* p = a.p[seg];
    float v = isf32 ? ((const float*)p)[off] : __bfloat162float(((const bf16*)p)[off]);
    dst[t] = v;
}

static __device__ __forceinline__ int ld_edge(const int* er, size_t i, int idx64) {
    return idx64 ? er[2 * i] : er[i];
}

// ---------------- CSR build ----------------

__global__ __launch_bounds__(256) void k_hist(const int* __restrict__ er, const int* __restrict__ flags,
                                              int* __restrict__ indeg, int E) {
    int e = blockIdx.x * 256 + threadIdx.x;
    if (e >= E) return;
    int idx64 = flags[1];
    int d = ld_edge(er, (size_t)E + e, idx64);
    atomicAdd(&indeg[d], 1);
}

__global__ __launch_bounds__(256) void k_scan1(const int* __restrict__ in, int* __restrict__ out,
                                               int* __restrict__ bsums, int n) {
    __shared__ int sm[256];
    int i = blockIdx.x * 256 + threadIdx.x;
    int v = (i < n) ? in[i] : 0;
    sm[threadIdx.x] = v;
    __syncthreads();
    for (int d = 1; d < 256; d <<= 1) {
        int t = (threadIdx.x >= d) ? sm[threadIdx.x - d] : 0;
        __syncthreads();
        sm[threadIdx.x] += t;
        __syncthreads();
    }
    if (i < n) out[i] = sm[threadIdx.x] - v;  // exclusive
    if (threadIdx.x == 255) bsums[blockIdx.x] = sm[255];
}

__global__ __launch_bounds__(1024) void k_scan2(int* __restrict__ bsums, int nb,
                                                int* __restrict__ csr_off, int N, int total) {
    __shared__ int sm[1024];
    int v = (threadIdx.x < nb) ? bsums[threadIdx.x] : 0;
    sm[threadIdx.x] = v;
    __syncthreads();
    for (int d = 1; d < 1024; d <<= 1) {
        int t = (threadIdx.x >= d) ? sm[threadIdx.x - d] : 0;
        __syncthreads();
        sm[threadIdx.x] += t;
        __syncthreads();
    }
    if (threadIdx.x < nb) bsums[threadIdx.x] = sm[threadIdx.x] - v;
    if (threadIdx.x == 0) csr_off[N] = total;
}

__global__ __launch_bounds__(256) void k_scan3(int* __restrict__ out, const int* __restrict__ bsums, int n) {
    int i = blockIdx.x * 256 + threadIdx.x;
    if (i < n) out[i] += bsums[blockIdx.x];
}

__global__ __launch_bounds__(256) void k_scatter(const int* __restrict__ er, const int* __restrict__ flags,
                                                 const int* __restrict__ off, int* __restrict__ cur,
                                                 int* __restrict__ csr, int E) {
    int e = blockIdx.x * 256 + threadIdx.x;
    if (e >= E) return;
    int idx64 = flags[1];
    int s = ld_edge(er, (size_t)e, idx64);
    int d = ld_edge(er, (size_t)E + e, idx64);
    int pos = off[d] + atomicAdd(&cur[d], 1);
    csr[pos] = s;
}

// ---------------- Layer 1: GATConv(3, 16, heads=4) ----------------

// one wave (64 lanes) per node; lane = head*16 + chan; h1 stored bf16
__global__ __launch_bounds__(256) void k_l1_transform(const float* __restrict__ x, const float* __restrict__ W1,
                                                      const float* __restrict__ att_s, const float* __restrict__ att_d,
                                                      unsigned short* __restrict__ h1b, float* __restrict__ as1,
                                                      float* __restrict__ ad1, int N) {
    int tid = threadIdx.x;
    int node = blockIdx.x * 4 + (tid >> 6);
    if (node >= N) return;
    int lane = tid & 63;
    float x0 = x[node * 3 + 0];
    float x1 = x[node * 3 + 1];
    float x2 = x[node * 3 + 2];
    float h = x0 * W1[lane] + x1 * W1[64 + lane] + x2 * W1[128 + lane];
    h1b[(size_t)node * 64 + lane] = f2us(h);
    float ts = h * att_s[lane];   // att_src1 is (4,16) flat == lane
    float td = h * att_d[lane];
    for (int m = 8; m >= 1; m >>= 1) { ts += __shfl_xor(ts, m); td += __shfl_xor(td, m); }
    if ((lane & 15) == 0) {
        as1[node * 4 + (lane >> 4)] = ts;
        ad1[node * 4 + (lane >> 4)] = td;
    }
}

__global__ __launch_bounds__(256) void k_l1_agg(const unsigned short* __restrict__ h1b, const float* __restrict__ as1,
                                                const float* __restrict__ ad1, const int* __restrict__ off,
                                                const int* __restrict__ csr, const float* __restrict__ b1,
                                                float* __restrict__ x1, int N) {
    int tid = threadIdx.x;
    int node = blockIdx.x * 4 + (tid >> 6);
    if (node >= N) return;
    int lane = tid & 63;
    int h = lane >> 4;
    float ad = ad1[node * 4 + h];
    int e0 = off[node], e1 = off[node + 1];
    // self-loop (s = node)
    float z = as1[node * 4 + h] + ad;
    z = (z > 0.f) ? z : 0.2f * z;
    float w = __expf(z);
    float den0 = w, den1 = 0.f;
    float acc0 = w * us2f(h1b[(size_t)node * 64 + lane]), acc1 = 0.f;
    int jj = e0;
    for (; jj + 2 <= e1; jj += 2) {
        int s0 = csr[jj], s1 = csr[jj + 1];
        float z0 = as1[s0 * 4 + h] + ad;
        float z1 = as1[s1 * 4 + h] + ad;
        float hv0 = us2f(h1b[(size_t)s0 * 64 + lane]);
        float hv1 = us2f(h1b[(size_t)s1 * 64 + lane]);
        z0 = (z0 > 0.f) ? z0 : 0.2f * z0;
        z1 = (z1 > 0.f) ? z1 : 0.2f * z1;
        float w0 = __expf(z0), w1 = __expf(z1);
        den0 += w0; acc0 += w0 * hv0;
        den1 += w1; acc1 += w1 * hv1;
    }
    if (jj < e1) {
        int s0 = csr[jj];
        float z0 = as1[s0 * 4 + h] + ad;
        z0 = (z0 > 0.f) ? z0 : 0.2f * z0;
        float w0 = __expf(z0);
        den0 += w0; acc0 += w0 * us2f(h1b[(size_t)s0 * 64 + lane]);
    }
    float o = (acc0 + acc1) / (den0 + den1 + 1e-16f) + b1[lane];
    x1[(size_t)node * 64 + lane] = (o > 0.f) ? o : 0.f;   // relu
}

// ---------------- Layer 2: GATv2Conv(64, 16, heads=2) ----------------

// one wave per node; lanes 0..31 -> hl (bf16 out), 32..63 -> hr (f32 out)
__global__ __launch_bounds__(256) void k_l2_transform(const float* __restrict__ x1,
                                                      const float* __restrict__ W2l, const float* __restrict__ b2l,
                                                      const float* __restrict__ W2r, const float* __restrict__ b2r,
                                                      unsigned short* __restrict__ hlb, float* __restrict__ hr, int N) {
    __shared__ float xs[4][64];
    int tid = threadIdx.x;
    int r = tid >> 6, c64 = tid & 63;
    int node = blockIdx.x * 4 + r;
    xs[r][c64] = (node < N) ? x1[(size_t)node * 64 + c64] : 0.f;
    __syncthreads();
    if (node >= N) return;
    int half = (tid >> 5) & 1;
    int j = tid & 31;
    const float* W = half ? W2r : W2l;
    float acc = half ? b2r[j] : b2l[j];
#pragma unroll
    for (int k = 0; k < 64; ++k) acc += xs[r][k] * W[k * 32 + j];
    if (half) hr[(size_t)node * 32 + j] = acc;
    else      hlb[(size_t)node * 32 + j] = f2us(acc);
}

// 32 lanes per node (2 nodes per wave); lane = head*16 + chan
__global__ __launch_bounds__(256) void k_l2_agg(const unsigned short* __restrict__ hlb, const float* __restrict__ hr,
                                                const float* __restrict__ att2, const float* __restrict__ b2,
                                                const int* __restrict__ off, const int* __restrict__ csr,
                                                float* __restrict__ x2, int N) {
    int tid = threadIdx.x;
    int node = blockIdx.x * 8 + (tid >> 5);
    if (node >= N) return;
    int sl = tid & 31;
    float hrd = hr[(size_t)node * 32 + sl];
    float a2 = att2[sl];          // att2 is (2,16) flat == sl
    int e0 = off[node], e1 = off[node + 1];
    // self-loop
    float hsf = us2f(hlb[(size_t)node * 32 + sl]);
    float e = hsf + hrd;
    e = (e > 0.f) ? e : 0.2f * e;
    float t = e * a2;
    t += __shfl_xor(t, 1); t += __shfl_xor(t, 2);
    t += __shfl_xor(t, 4); t += __shfl_xor(t, 8);
    float w = __expf(t);
    float den0 = w, den1 = 0.f;
    float acc0 = w * hsf, acc1 = 0.f;
    int jj = e0;
    for (; jj + 2 <= e1; jj += 2) {
        int s0 = csr[jj], s1 = csr[jj + 1];
        float h0 = us2f(hlb[(size_t)s0 * 32 + sl]);
        float h1v = us2f(hlb[(size_t)s1 * 32 + sl]);
        float e0v = h0 + hrd, e1v = h1v + hrd;
        e0v = (e0v > 0.f) ? e0v : 0.2f * e0v;
        e1v = (e1v > 0.f) ? e1v : 0.2f * e1v;
        float t0 = e0v * a2, t1 = e1v * a2;
        t0 += __shfl_xor(t0, 1); t1 += __shfl_xor(t1, 1);
        t0 += __shfl_xor(t0, 2); t1 += __shfl_xor(t1, 2);
        t0 += __shfl_xor(t0, 4); t1 += __shfl_xor(t1, 4);
        t0 += __shfl_xor(t0, 8); t1 += __shfl_xor(t1, 8);
        float w0 = __expf(t0), w1 = __expf(t1);
        den0 += w0; acc0 += w0 * h0;
        den1 += w1; acc1 += w1 * h1v;
    }
    if (jj < e1) {
        int s0 = csr[jj];
        float h0 = us2f(hlb[(size_t)s0 * 32 + sl]);
        float e0v = h0 + hrd;
        e0v = (e0v > 0.f) ? e0v : 0.2f * e0v;
        float t0 = e0v * a2;
        t0 += __shfl_xor(t0, 1); t0 += __shfl_xor(t0, 2);
        t0 += __shfl_xor(t0, 4); t0 += __shfl_xor(t0, 8);
        float w0 = __expf(t0);
        den0 += w0; acc0 += w0 * h0;
    }
    x2[(size_t)node * 32 + sl] = (acc0 + acc1) / (den0 + den1 + 1e-16f) + b2[sl];
}

// ---------------- Layer 3: TransformerConv(32, 7, heads=1) ----------------

// 32 lanes per node; j<28 active: m = j/7 selects q/k/v/skip, c = j%7
__global__ __launch_bounds__(256) void k_l3_transform(const float* __restrict__ x2,
                                                      const float* __restrict__ Wq, const float* __restrict__ bq,
                                                      const float* __restrict__ Wk, const float* __restrict__ bk,
                                                      const float* __restrict__ Wv, const float* __restrict__ bv,
                                                      const float* __restrict__ Wsk, const float* __restrict__ bsk,
                                                      float* __restrict__ Q, float* __restrict__ K,
                                                      float* __restrict__ V, float* __restrict__ SK, int N) {
    __shared__ float xs[8][32];
    int tid = threadIdx.x;
    int r = tid >> 5, cc = tid & 31;
    int node = blockIdx.x * 8 + r;
    xs[r][cc] = (node < N) ? x2[(size_t)node * 32 + cc] : 0.f;
    __syncthreads();
    if (node >= N) return;
    int j = tid & 31;
    if (j >= 28) return;
    int m = j / 7, c = j - m * 7;
    const float* W = (m == 0) ? Wq : (m == 1) ? Wk : (m == 2) ? Wv : Wsk;
    const float* B = (m == 0) ? bq : (m == 1) ? bk : (m == 2) ? bv : bsk;
    float acc = B[c];
#pragma unroll
    for (int k = 0; k < 32; ++k) acc += xs[r][k] * W[k * 7 + c];
    float* outp = (m == 0) ? Q : (m == 1) ? K : (m == 2) ? V : SK;
    outp[(size_t)node * 7 + c] = acc;
}

// 8 lanes per node (8 nodes per wave); no self-loops in layer 3
__global__ __launch_bounds__(256) void k_l3_agg(const float* __restrict__ Q, const float* __restrict__ K,
                                                const float* __restrict__ V, const float* __restrict__ SK,
                                                const int* __restrict__ off, const int* __restrict__ csr,
                                                float* __restrict__ out, int N) {
    int tid = threadIdx.x;
    int node = blockIdx.x * 32 + (tid >> 3);
    if (node >= N) return;
    int sl = tid & 7;
    bool act = sl < 7;
    float qd = act ? Q[(size_t)node * 7 + sl] : 0.f;
    float acc = 0.f, den = 0.f;
    int e0 = off[node], e1 = off[node + 1];
    const float scale = 0.3779644730092272f;  // 1/sqrt(7)
    for (int jj = e0; jj < e1; ++jj) {
        int s = csr[jj];
        float t = act ? qd * K[(size_t)s * 7 + sl] : 0.f;
        t += __shfl_xor(t, 1); t += __shfl_xor(t, 2); t += __shfl_xor(t, 4);
        float w = __expf(t * scale);
        den += w;
        if (act) acc += w * V[(size_t)s * 7 + sl];
    }
    if (act) out[(size_t)node * 7 + sl] = acc / (den + 1e-16f) + SK[(size_t)node * 7 + sl];
}

// ---------------- launcher ----------------

extern "C" void kernel_launch(void* const* d_in, const int* in_sizes, int n_in,
                              void* d_out, int out_size, void* d_ws, size_t ws_size,
                              hipStream_t stream) {
    const int* ei = (const int*)d_in[1];
    float* out = (float*)d_out;

    int N = in_sizes[0] / 3;
    int E = in_sizes[1] / 2;
    int nb = (N + 255) / 256;   // assumed <= 1024 (N <= 262144)

    char* ws = (char*)d_ws;
    size_t o = 0;
    auto take = [&](size_t bytes) -> char* {
        char* p = ws + o;
        o = (o + bytes + 255) & ~(size_t)255;
        return p;
    };
    int*   flags   = (int*)take(64);
    int total_f = 0;
    for (int i = 0; i < 20; ++i) if (i != 1) total_f += in_sizes[i];
    float* canon  = (float*)take((size_t)total_f * 4);
    int*   csr_off = (int*)take((size_t)(N + 1) * 4);
    int*   indeg   = (int*)take((size_t)N * 4);
    int*   cursor  = (int*)take((size_t)N * 4);
    int*   bsums   = (int*)take((size_t)nb * 4);
    int*   csr_src = (int*)take((size_t)E * 4);
    float* bufA    = (float*)take((size_t)N * 64 * 4);  // h1b -> hlb|hr -> q|k|v|skip
    float* as1     = (float*)take((size_t)N * 4 * 4);
    float* ad1     = (float*)take((size_t)N * 4 * 4);
    float* bufB    = (float*)take((size_t)N * 64 * 4);  // x1 -> x2
    (void)ws_size; (void)n_in; (void)out_size;

    CvtArgs ca;
    const float* cp[20];
    {
        int off_ = 0, k = 0;
        for (int i = 0; i < 20; ++i) {
            if (i == 1) { cp[i] = nullptr; continue; }
            ca.p[k] = d_in[i];
            ca.sz[k] = in_sizes[i];
            cp[i] = canon + off_;
            off_ += in_sizes[i];
            ++k;
        }
    }

    hipMemsetAsync(indeg, 0, (size_t)N * 4, stream);
    hipMemsetAsync(cursor, 0, (size_t)N * 4, stream);

    k_detect<<<1, 256, 0, stream>>>((const unsigned short*)d_in[0], ei, flags);
    k_convert<<<(total_f + 255) / 256, 256, 0, stream>>>(ca, flags, canon, total_f);

    int ge = (E + 255) / 256;
    k_hist<<<ge, 256, 0, stream>>>(ei, flags, indeg, E);
    k_scan1<<<nb, 256, 0, stream>>>(indeg, csr_off, bsums, N);
    k_scan2<<<1, 1024, 0, stream>>>(bsums, nb, csr_off, N, E);
    k_scan3<<<nb, 256, 0, stream>>>(csr_off, bsums, N);
    k_scatter<<<ge, 256, 0, stream>>>(ei, flags, csr_off, cursor, csr_src, E);

    unsigned short* h1b = (unsigned short*)bufA;                 // N*64 bf16 = 12.8 MB
    k_l1_transform<<<(N + 3) / 4, 256, 0, stream>>>(cp[0], cp[2], cp[3], cp[4], h1b, as1, ad1, N);
    float* x1 = bufB;
    k_l1_agg<<<(N + 3) / 4, 256, 0, stream>>>(h1b, as1, ad1, csr_off, csr_src, cp[5], x1, N);

    unsigned short* hlb = (unsigned short*)bufA;                 // N*32 bf16 = 6.4 MB
    float* hr = bufA + (size_t)N * 16;                           // after hlb (N*32*2B = N*16 floats)
    k_l2_transform<<<(N + 3) / 4, 256, 0, stream>>>(x1, cp[6], cp[7], cp[8], cp[9], hlb, hr, N);
    float* x2 = bufB;
    k_l2_agg<<<(N + 7) / 8, 256, 0, stream>>>(hlb, hr, cp[10], cp[11], csr_off, csr_src, x2, N);

    float* Q  = bufA;
    float* K  = bufA + (size_t)N * 7;
    float* V  = bufA + (size_t)N * 14;
    float* SK = bufA + (size_t)N * 21;
    k_l3_transform<<<(N + 7) / 8, 256, 0, stream>>>(x2, cp[12], cp[13], cp[14], cp[15], cp[16], cp[17],
                                                    cp[18], cp[19], Q, K, V, SK, N);
    k_l3_agg<<<(N + 31) / 32, 256, 0, stream>>>(Q, K, V, SK, csr_off, csr_src, out, N);
}

// Round 4
// 500.227 us; speedup vs baseline: 1.5422x; 1.3062x over previous
//
#include <hip/hip_runtime.h>
#include <hip/hip_bf16.h>

typedef __hip_bfloat16 bf16;

static __device__ __forceinline__ float us2f(unsigned short u) {
    union { unsigned int i; float f; } c; c.i = ((unsigned int)u) << 16; return c.f;
}
static __device__ __forceinline__ unsigned short f2us(float f) {
    union { float f; unsigned int i; } c; c.f = f;
    unsigned int r = c.i + 0x7FFF + ((c.i >> 16) & 1);   // round-to-nearest-even
    return (unsigned short)(r >> 16);
}

// ---------------- dtype probe + canonicalization ----------------
// flags[0] = 1 if float tensors are stored as f32 (else bf16)
// flags[1] = 1 if edge_index is stored as int64 (else int32)

__global__ __launch_bounds__(256) void k_detect(const unsigned short* __restrict__ xr,
                                                const int* __restrict__ er,
                                                int* __restrict__ flags) {
    __shared__ int sbad, snz;
    int tid = threadIdx.x;
    if (tid == 0) { sbad = 0; snz = 0; }
    __syncthreads();
    int bad = 0, nz = 0;
    for (int i = tid; i < 1024; i += 256) {
        unsigned short w = xr[2 * i];          // f32 storage: low mantissa half (uniform); bf16: real value
        int ex = (w >> 7) & 0xFF;
        if (ex < 110 || ex > 135) bad++;
        if (er[2 * i + 1] != 0) nz++;          // int64 storage: high words of small values == 0
    }
    atomicAdd(&sbad, bad);
    atomicAdd(&snz, nz);
    __syncthreads();
    if (tid == 0) {
        flags[0] = (sbad > 256) ? 1 : 0;
        flags[1] = (snz < 512) ? 1 : 0;
    }
}

struct CvtArgs { const void* p[19]; int sz[19]; };

__global__ __launch_bounds__(256) void k_convert(CvtArgs a, const int* __restrict__ flags,
                                                 float* __restrict__ dst, int total) {
    int t = blockIdx.x * 256 + threadIdx.x;
    if (t >= total) return;
    int isf32 = flags[0];
    int base = 0, seg = -1, off = 0;
#pragma unroll
    for (int i = 0; i < 19; i++) {
        if (seg < 0 && t < base + a.sz[i]) { seg = i; off = t - base; }
        base += a.sz[i];
    }
    const void* p = a.p[seg];
    float v = isf32 ? ((const float*)p)[off] : __bfloat162float(((const bf16*)p)[off]);
    dst[t] = v;
}

static __device__ __forceinline__ int ld_edge(const int* er, size_t i, int idx64) {
    return idx64 ? er[2 * i] : er[i];
}

// ---------------- bucketed CSR build ----------------
// bucket b = dst >> 10 (1024 nodes per bucket), NB <= 256 assumed (N <= 262144)

// Pass A: global per-bucket edge counts
__global__ __launch_bounds__(1024) void k_bhist(const int* __restrict__ er, const int* __restrict__ flags,
                                                int* __restrict__ bcnt, int E, int NB) {
    __shared__ int cnt[256];
    int tid = threadIdx.x;
    if (tid < 256) cnt[tid] = 0;
    __syncthreads();
    int idx64 = flags[1];
    int base = blockIdx.x * 4096 + tid;
#pragma unroll
    for (int k = 0; k < 4; ++k) {
        int e = base + k * 1024;
        if (e < E) {
            int d = ld_edge(er, (size_t)E + e, idx64);
            atomicAdd(&cnt[d >> 10], 1);
        }
    }
    __syncthreads();
    if (tid < NB && cnt[tid]) atomicAdd(&bcnt[tid], cnt[tid]);
}

// Pass B: scan bucket counts -> bbase (exclusive), init bcur, csr_off[N]=E
__global__ __launch_bounds__(256) void k_bscan(const int* __restrict__ bcnt, int* __restrict__ bbase,
                                               int* __restrict__ bcur, int* __restrict__ csr_off,
                                               int NB, int N, int E) {
    __shared__ int sm[256];
    int tid = threadIdx.x;
    int v = (tid < NB) ? bcnt[tid] : 0;
    sm[tid] = v;
    __syncthreads();
    for (int d = 1; d < 256; d <<= 1) {
        int t = (tid >= d) ? sm[tid - d] : 0;
        __syncthreads();
        sm[tid] += t;
        __syncthreads();
    }
    int excl = sm[tid] - v;
    if (tid < NB) { bbase[tid] = excl; bcur[tid] = excl; }
    if (tid == 0) { bbase[NB] = E; csr_off[N] = E; }
}

// Pass C: scatter (src,dst) into bucket-contiguous regions with per-block reservations
__global__ __launch_bounds__(1024) void k_bscatter(const int* __restrict__ er, const int* __restrict__ flags,
                                                   int* __restrict__ bcur, int2* __restrict__ bkt,
                                                   int E, int NB) {
    __shared__ int cnt[256];
    __shared__ int res[256];
    int tid = threadIdx.x;
    if (tid < 256) cnt[tid] = 0;
    __syncthreads();
    int idx64 = flags[1];
    int base = blockIdx.x * 4096 + tid;
    int sv[4], dv[4], bv[4];
    bool val[4];
#pragma unroll
    for (int k = 0; k < 4; ++k) {
        int e = base + k * 1024;
        val[k] = (e < E);
        if (val[k]) {
            sv[k] = ld_edge(er, (size_t)e, idx64);
            dv[k] = ld_edge(er, (size_t)E + e, idx64);
            bv[k] = dv[k] >> 10;
            atomicAdd(&cnt[bv[k]], 1);
        }
    }
    __syncthreads();
    if (tid < NB) {
        int c = cnt[tid];
        res[tid] = c ? atomicAdd(&bcur[tid], c) : 0;
        cnt[tid] = 0;
    }
    __syncthreads();
#pragma unroll
    for (int k = 0; k < 4; ++k) {
        if (val[k]) {
            int r = atomicAdd(&cnt[bv[k]], 1);
            bkt[res[bv[k]] + r] = make_int2(sv[k], dv[k]);
        }
    }
}

// Pass D: per-bucket indeg count + scan -> csr_off; scatter src -> csr
__global__ __launch_bounds__(1024) void k_bbuild(const int2* __restrict__ bkt, const int* __restrict__ bbase,
                                                 int* __restrict__ csr_off, int* __restrict__ csr, int N) {
    __shared__ int sm[1024];
    int b = blockIdx.x, tid = threadIdx.x;
    int node0 = b << 10;
    int n0 = bbase[b], n1 = bbase[b + 1];
    int m = n1 - n0;
    sm[tid] = 0;
    __syncthreads();
    const int2* bp = bkt + n0;
    for (int i = tid; i < m; i += 1024) atomicAdd(&sm[bp[i].y - node0], 1);
    __syncthreads();
    int v = sm[tid];
    for (int d = 1; d < 1024; d <<= 1) {
        int t = (tid >= d) ? sm[tid - d] : 0;
        __syncthreads();
        sm[tid] += t;
        __syncthreads();
    }
    int excl = sm[tid] - v;
    int node = node0 + tid;
    if (node < N) csr_off[node] = n0 + excl;
    __syncthreads();
    sm[tid] = excl;
    __syncthreads();
    for (int i = tid; i < m; i += 1024) {
        int2 sd = bp[i];
        int r = atomicAdd(&sm[sd.y - node0], 1);
        csr[n0 + r] = sd.x;
    }
}

// ---------------- Layer 1: GATConv(3, 16, heads=4) ----------------

// one wave (64 lanes) per node; lane = head*16 + chan; h1 stored bf16
__global__ __launch_bounds__(256) void k_l1_transform(const float* __restrict__ x, const float* __restrict__ W1,
                                                      const float* __restrict__ att_s, const float* __restrict__ att_d,
                                                      unsigned short* __restrict__ h1b, float* __restrict__ as1,
                                                      float* __restrict__ ad1, int N) {
    int tid = threadIdx.x;
    int node = blockIdx.x * 4 + (tid >> 6);
    if (node >= N) return;
    int lane = tid & 63;
    float x0 = x[node * 3 + 0];
    float x1 = x[node * 3 + 1];
    float x2 = x[node * 3 + 2];
    float h = x0 * W1[lane] + x1 * W1[64 + lane] + x2 * W1[128 + lane];
    h1b[(size_t)node * 64 + lane] = f2us(h);
    float ts = h * att_s[lane];   // att_src1 is (4,16) flat == lane
    float td = h * att_d[lane];
    for (int m = 8; m >= 1; m >>= 1) { ts += __shfl_xor(ts, m); td += __shfl_xor(td, m); }
    if ((lane & 15) == 0) {
        as1[node * 4 + (lane >> 4)] = ts;
        ad1[node * 4 + (lane >> 4)] = td;
    }
}

__global__ __launch_bounds__(256) void k_l1_agg(const unsigned short* __restrict__ h1b, const float* __restrict__ as1,
                                                const float* __restrict__ ad1, const int* __restrict__ off,
                                                const int* __restrict__ csr, const float* __restrict__ b1,
                                                float* __restrict__ x1, int N) {
    int tid = threadIdx.x;
    int node = blockIdx.x * 4 + (tid >> 6);
    if (node >= N) return;
    int lane = tid & 63;
    int h = lane >> 4;
    float ad = ad1[node * 4 + h];
    int e0 = off[node], e1 = off[node + 1];
    // self-loop (s = node)
    float z = as1[node * 4 + h] + ad;
    z = (z > 0.f) ? z : 0.2f * z;
    float w = __expf(z);
    float den0 = w, den1 = 0.f, den2 = 0.f, den3 = 0.f;
    float acc0 = w * us2f(h1b[(size_t)node * 64 + lane]), acc1 = 0.f, acc2 = 0.f, acc3 = 0.f;
    int jj = e0;
    for (; jj + 4 <= e1; jj += 4) {
        int s0 = csr[jj], s1 = csr[jj + 1], s2 = csr[jj + 2], s3 = csr[jj + 3];
        float z0 = as1[s0 * 4 + h] + ad;
        float z1 = as1[s1 * 4 + h] + ad;
        float z2 = as1[s2 * 4 + h] + ad;
        float z3 = as1[s3 * 4 + h] + ad;
        float hv0 = us2f(h1b[(size_t)s0 * 64 + lane]);
        float hv1 = us2f(h1b[(size_t)s1 * 64 + lane]);
        float hv2 = us2f(h1b[(size_t)s2 * 64 + lane]);
        float hv3 = us2f(h1b[(size_t)s3 * 64 + lane]);
        z0 = (z0 > 0.f) ? z0 : 0.2f * z0;
        z1 = (z1 > 0.f) ? z1 : 0.2f * z1;
        z2 = (z2 > 0.f) ? z2 : 0.2f * z2;
        z3 = (z3 > 0.f) ? z3 : 0.2f * z3;
        float w0 = __expf(z0), w1 = __expf(z1), w2 = __expf(z2), w3 = __expf(z3);
        den0 += w0; acc0 += w0 * hv0;
        den1 += w1; acc1 += w1 * hv1;
        den2 += w2; acc2 += w2 * hv2;
        den3 += w3; acc3 += w3 * hv3;
    }
    for (; jj < e1; ++jj) {
        int s0 = csr[jj];
        float z0 = as1[s0 * 4 + h] + ad;
        z0 = (z0 > 0.f) ? z0 : 0.2f * z0;
        float w0 = __expf(z0);
        den0 += w0; acc0 += w0 * us2f(h1b[(size_t)s0 * 64 + lane]);
    }
    float o = (acc0 + acc1 + acc2 + acc3) / (den0 + den1 + den2 + den3 + 1e-16f) + b1[lane];
    x1[(size_t)node * 64 + lane] = (o > 0.f) ? o : 0.f;   // relu
}

// ---------------- Layer 2: GATv2Conv(64, 16, heads=2) ----------------

// one wave per node; lanes 0..31 -> hl (bf16 out), 32..63 -> hr (f32 out)
__global__ __launch_bounds__(256) void k_l2_transform(const float* __restrict__ x1,
                                                      const float* __restrict__ W2l, const float* __restrict__ b2l,
                                                      const float* __restrict__ W2r, const float* __restrict__ b2r,
                                                      unsigned short* __restrict__ hlb, float* __restrict__ hr, int N) {
    __shared__ float xs[4][64];
    int tid = threadIdx.x;
    int r = tid >> 6, c64 = tid & 63;
    int node = blockIdx.x * 4 + r;
    xs[r][c64] = (node < N) ? x1[(size_t)node * 64 + c64] : 0.f;
    __syncthreads();
    if (node >= N) return;
    int half = (tid >> 5) & 1;
    int j = tid & 31;
    const float* W = half ? W2r : W2l;
    float acc = half ? b2r[j] : b2l[j];
#pragma unroll
    for (int k = 0; k < 64; ++k) acc += xs[r][k] * W[k * 32 + j];
    if (half) hr[(size_t)node * 32 + j] = acc;
    else      hlb[(size_t)node * 32 + j] = f2us(acc);
}

// 32 lanes per node (2 nodes per wave); lane = head*16 + chan
__global__ __launch_bounds__(256) void k_l2_agg(const unsigned short* __restrict__ hlb, const float* __restrict__ hr,
                                                const float* __restrict__ att2, const float* __restrict__ b2,
                                                const int* __restrict__ off, const int* __restrict__ csr,
                                                float* __restrict__ x2, int N) {
    int tid = threadIdx.x;
    int node = blockIdx.x * 8 + (tid >> 5);
    if (node >= N) return;
    int sl = tid & 31;
    float hrd = hr[(size_t)node * 32 + sl];
    float a2 = att2[sl];          // att2 is (2,16) flat == sl
    int e0 = off[node], e1 = off[node + 1];
    // self-loop
    float hsf = us2f(hlb[(size_t)node * 32 + sl]);
    float e = hsf + hrd;
    e = (e > 0.f) ? e : 0.2f * e;
    float t = e * a2;
    t += __shfl_xor(t, 1); t += __shfl_xor(t, 2);
    t += __shfl_xor(t, 4); t += __shfl_xor(t, 8);
    float w = __expf(t);
    float den0 = w, den1 = 0.f;
    float acc0 = w * hsf, acc1 = 0.f;
    int jj = e0;
    for (; jj + 2 <= e1; jj += 2) {
        int s0 = csr[jj], s1 = csr[jj + 1];
        float h0 = us2f(hlb[(size_t)s0 * 32 + sl]);
        float h1v = us2f(hlb[(size_t)s1 * 32 + sl]);
        float e0v = h0 + hrd, e1v = h1v + hrd;
        e0v = (e0v > 0.f) ? e0v : 0.2f * e0v;
        e1v = (e1v > 0.f) ? e1v : 0.2f * e1v;
        float t0 = e0v * a2, t1 = e1v * a2;
        t0 += __shfl_xor(t0, 1); t1 += __shfl_xor(t1, 1);
        t0 += __shfl_xor(t0, 2); t1 += __shfl_xor(t1, 2);
        t0 += __shfl_xor(t0, 4); t1 += __shfl_xor(t1, 4);
        t0 += __shfl_xor(t0, 8); t1 += __shfl_xor(t1, 8);
        float w0 = __expf(t0), w1 = __expf(t1);
        den0 += w0; acc0 += w0 * h0;
        den1 += w1; acc1 += w1 * h1v;
    }
    if (jj < e1) {
        int s0 = csr[jj];
        float h0 = us2f(hlb[(size_t)s0 * 32 + sl]);
        float e0v = h0 + hrd;
        e0v = (e0v > 0.f) ? e0v : 0.2f * e0v;
        float t0 = e0v * a2;
        t0 += __shfl_xor(t0, 1); t0 += __shfl_xor(t0, 2);
        t0 += __shfl_xor(t0, 4); t0 += __shfl_xor(t0, 8);
        float w0 = __expf(t0);
        den0 += w0; acc0 += w0 * h0;
    }
    x2[(size_t)node * 32 + sl] = (acc0 + acc1) / (den0 + den1 + 1e-16f) + b2[sl];
}

// ---------------- Layer 3: TransformerConv(32, 7, heads=1) ----------------

// 32 lanes per node; j<28 active: m = j/7 selects q/k/v/skip, c = j%7
__global__ __launch_bounds__(256) void k_l3_transform(const float* __restrict__ x2,
                                                      const float* __restrict__ Wq, const float* __restrict__ bq,
                                                      const float* __restrict__ Wk, const float* __restrict__ bk,
                                                      const float* __restrict__ Wv, const float* __restrict__ bv,
                                                      const float* __restrict__ Wsk, const float* __restrict__ bsk,
                                                      float* __restrict__ Q, float* __restrict__ K,
                                                      float* __restrict__ V, float* __restrict__ SK, int N) {
    __shared__ float xs[8][32];
    int tid = threadIdx.x;
    int r = tid >> 5, cc = tid & 31;
    int node = blockIdx.x * 8 + r;
    xs[r][cc] = (node < N) ? x2[(size_t)node * 32 + cc] : 0.f;
    __syncthreads();
    if (node >= N) return;
    int j = tid & 31;
    if (j >= 28) return;
    int m = j / 7, c = j - m * 7;
    const float* W = (m == 0) ? Wq : (m == 1) ? Wk : (m == 2) ? Wv : Wsk;
    const float* B = (m == 0) ? bq : (m == 1) ? bk : (m == 2) ? bv : bsk;
    float acc = B[c];
#pragma unroll
    for (int k = 0; k < 32; ++k) acc += xs[r][k] * W[k * 7 + c];
    float* outp = (m == 0) ? Q : (m == 1) ? K : (m == 2) ? V : SK;
    outp[(size_t)node * 7 + c] = acc;
}

// 8 lanes per node (8 nodes per wave); no self-loops in layer 3
__global__ __launch_bounds__(256) void k_l3_agg(const float* __restrict__ Q, const float* __restrict__ K,
                                                const float* __restrict__ V, const float* __restrict__ SK,
                                                const int* __restrict__ off, const int* __restrict__ csr,
                                                float* __restrict__ out, int N) {
    int tid = threadIdx.x;
    int node = blockIdx.x * 32 + (tid >> 3);
    if (node >= N) return;
    int sl = tid & 7;
    bool act = sl < 7;
    float qd = act ? Q[(size_t)node * 7 + sl] : 0.f;
    float acc = 0.f, den = 0.f;
    int e0 = off[node], e1 = off[node + 1];
    const float scale = 0.3779644730092272f;  // 1/sqrt(7)
    for (int jj = e0; jj < e1; ++jj) {
        int s = csr[jj];
        float t = act ? qd * K[(size_t)s * 7 + sl] : 0.f;
        t += __shfl_xor(t, 1); t += __shfl_xor(t, 2); t += __shfl_xor(t, 4);
        float w = __expf(t * scale);
        den += w;
        if (act) acc += w * V[(size_t)s * 7 + sl];
    }
    if (act) out[(size_t)node * 7 + sl] = acc / (den + 1e-16f) + SK[(size_t)node * 7 + sl];
}

// ---------------- launcher ----------------

extern "C" void kernel_launch(void* const* d_in, const int* in_sizes, int n_in,
                              void* d_out, int out_size, void* d_ws, size_t ws_size,
                              hipStream_t stream) {
    const int* ei = (const int*)d_in[1];
    float* out = (float*)d_out;

    int N = in_sizes[0] / 3;
    int E = in_sizes[1] / 2;
    int NB = (N + 1023) >> 10;   // assumed <= 256 (N <= 262144)

    char* ws = (char*)d_ws;
    size_t o = 0;
    auto take = [&](size_t bytes) -> char* {
        char* p = ws + o;
        o = (o + bytes + 255) & ~(size_t)255;
        return p;
    };
    int*   flags   = (int*)take(64);
    int total_f = 0;
    for (int i = 0; i < 20; ++i) if (i != 1) total_f += in_sizes[i];
    float* canon   = (float*)take((size_t)total_f * 4);
    int*   csr_off = (int*)take((size_t)(N + 1) * 4);
    int*   bcnt    = (int*)take(256 * 4);
    int*   bbase   = (int*)take(257 * 4);
    int*   bcur    = (int*)take(256 * 4);
    int*   csr     = (int*)take((size_t)E * 4);
    float* bufA    = (float*)take((size_t)N * 64 * 4);  // h1b -> hlb|hr -> q|k|v|skip
    float* as1     = (float*)take((size_t)N * 4 * 4);
    float* ad1     = (float*)take((size_t)N * 4 * 4);
    float* bufB    = (float*)take((size_t)N * 64 * 4);  // bkt -> x1 -> x2
    (void)ws_size; (void)n_in; (void)out_size;

    CvtArgs ca;
    const float* cp[20];
    {
        int off_ = 0, k = 0;
        for (int i = 0; i < 20; ++i) {
            if (i == 1) { cp[i] = nullptr; continue; }
            ca.p[k] = d_in[i];
            ca.sz[k] = in_sizes[i];
            cp[i] = canon + off_;
            off_ += in_sizes[i];
            ++k;
        }
    }

    hipMemsetAsync(bcnt, 0, 256 * 4, stream);
    k_detect<<<1, 256, 0, stream>>>((const unsigned short*)d_in[0], ei, flags);
    k_convert<<<(total_f + 255) / 256, 256, 0, stream>>>(ca, flags, canon, total_f);

    // bkt aliases bufB (E*8 bytes <= N*256 bytes for E <= 32N); x1 written only after k_bbuild
    int2* bkt = (int2*)bufB;
    int gb = (E + 4095) / 4096;
    k_bhist<<<gb, 1024, 0, stream>>>(ei, flags, bcnt, E, NB);
    k_bscan<<<1, 256, 0, stream>>>(bcnt, bbase, bcur, csr_off, NB, N, E);
    k_bscatter<<<gb, 1024, 0, stream>>>(ei, flags, bcur, bkt, E, NB);
    k_bbuild<<<NB, 1024, 0, stream>>>(bkt, bbase, csr_off, csr, N);

    unsigned short* h1b = (unsigned short*)bufA;                 // N*64 bf16 = 12.8 MB
    k_l1_transform<<<(N + 3) / 4, 256, 0, stream>>>(cp[0], cp[2], cp[3], cp[4], h1b, as1, ad1, N);
    float* x1 = bufB;
    k_l1_agg<<<(N + 3) / 4, 256, 0, stream>>>(h1b, as1, ad1, csr_off, csr, cp[5], x1, N);

    unsigned short* hlb = (unsigned short*)bufA;                 // N*32 bf16 = 6.4 MB
    float* hr = bufA + (size_t)N * 16;                           // after hlb (N*32*2B = N*16 floats)
    k_l2_transform<<<(N + 3) / 4, 256, 0, stream>>>(x1, cp[6], cp[7], cp[8], cp[9], hlb, hr, N);
    float* x2 = bufB;
    k_l2_agg<<<(N + 7) / 8, 256, 0, stream>>>(hlb, hr, cp[10], cp[11], csr_off, csr, x2, N);

    float* Q  = bufA;
    float* K  = bufA + (size_t)N * 7;
    float* V  = bufA + (size_t)N * 14;
    float* SK = bufA + (size_t)N * 21;
    k_l3_transform<<<(N + 7) / 8, 256, 0, stream>>>(x2, cp[12], cp[13], cp[14], cp[15], cp[16], cp[17],
                                                    cp[18], cp[19], Q, K, V, SK, N);
    k_l3_agg<<<(N + 31) / 32, 256, 0, stream>>>(Q, K, V, SK, csr_off, csr, out, N);
}